// Round 1
// baseline (400.834 us; speedup 1.0000x reference)
//
#include <hip/hip_runtime.h>
#include <math.h>

// Sinkhorn loss, B=16 batches of N=1536 1D points, fp32.
// 18 softmin rounds: round 0 = init (h = b_log), rounds 1..16 = scan steps
// (Jacobi update, f_new = 0.5*(f_old + ft)), round 17 = final extrapolation
// at eps = blur^2 fused with the mean/sum reduction into d_out[0].
//
// ws layout (floats): eps0[16] | F0[B*N] | F1[B*N] | G0[B*N] | G1[B*N]

static constexpr int   BN    = 16;
static constexpr int   NP    = 1536;
static constexpr float BLUR2 = 0.0025f;                 // blur^2
static constexpr float L2E   = 1.4426950408889634f;     // log2(e)
static constexpr float LN2   = 0.6931471805599453f;     // ln(2)
static constexpr float HLOG  = -7.33693691f;            // -log(1536)

#if defined(__has_builtin)
#if __has_builtin(__builtin_amdgcn_exp2f)
#define EXP2F(x) __builtin_amdgcn_exp2f(x)
#else
#define EXP2F(x) exp2f(x)
#endif
#else
#define EXP2F(x) exp2f(x)
#endif

__global__ __launch_bounds__(256) void sk_setup(const float* __restrict__ x,
                                                const float* __restrict__ y,
                                                float* __restrict__ eps0) {
    const int b = blockIdx.x;
    const int t = threadIdx.x;
    float mn = INFINITY, mx = -INFINITY;
    for (int j = t; j < NP; j += 256) {
        float xv = x[b * NP + j], yv = y[b * NP + j];
        mn = fminf(mn, fminf(xv, yv));
        mx = fmaxf(mx, fmaxf(xv, yv));
    }
    for (int o = 1; o < 64; o <<= 1) {
        mn = fminf(mn, __shfl_xor(mn, o));
        mx = fmaxf(mx, __shfl_xor(mx, o));
    }
    __shared__ float smn[4], smx[4];
    const int w = t >> 6;
    if ((t & 63) == 0) { smn[w] = mn; smx[w] = mx; }
    __syncthreads();
    if (t == 0) {
        mn = fminf(fminf(smn[0], smn[1]), fminf(smn[2], smn[3]));
        mx = fmaxf(fmaxf(smx[0], smx[1]), fmaxf(smx[2], smx[3]));
        float d = mx - mn;
        eps0[b] = d * d;
    }
}

// grid = 768 blocks: batch (16) x {dir f: 24, dir g: 24} row-blocks of 64 rows.
// 4 lanes cooperate per output row (two-pass LSE over LDS column table).
__global__ __launch_bounds__(256) void sk_round(const float* __restrict__ x,
                                                const float* __restrict__ y,
                                                float* __restrict__ ws,
                                                float* __restrict__ out,
                                                int round) {
    __shared__ __align__(16) float2 cu[NP];   // (col_coord_j, U_j) ; 12 KB
    __shared__ float wsum[4];

    const int blk    = blockIdx.x;       // 0..767
    const int batch  = blk / 48;
    const int rb     = blk % 48;
    const int dir    = (rb < 24) ? 0 : 1;
    const int rowblk = rb - dir * 24;    // 0..23

    float* F0 = ws + 16;
    float* F1 = F0 + BN * NP;
    float* G0 = F1 + BN * NP;
    float* G1 = G0 + BN * NP;
    const int ri = (round + 1) & 1;      // read parity
    const int wi = round & 1;            // write parity
    float* Fr = ri ? F1 : F0;  float* Fw = wi ? F1 : F0;
    float* Gr = ri ? G1 : G0;  float* Gw = wi ? G1 : G0;

    const float* colc; const float* rowc; const float* hsrc;
    float* obuf; const float* oldb;
    if (dir == 0) { // ft rows: rows over x_i, cols over y_j, h from g
        colc = y + batch * NP; rowc = x + batch * NP;
        hsrc = Gr + batch * NP; obuf = Fw + batch * NP; oldb = Fr + batch * NP;
    } else {        // gt rows: rows over y_i, cols over x_j, h from f
        colc = x + batch * NP; rowc = y + batch * NP;
        hsrc = Fr + batch * NP; obuf = Gw + batch * NP; oldb = Gr + batch * NP;
    }

    // eps schedule: eps_k = max(blur^2, eps0 * 0.25^max(k-1,0)); round r in
    // [1,16] is scan step k=r-1; round 0 uses eps_arr[0]; round 17 uses blur^2.
    const float e0 = ws[batch];
    float eps;
    if (round == 0)       eps = fmaxf(BLUR2, e0);
    else if (round >= 17) eps = BLUR2;
    else {
        int mk = round - 2; if (mk < 0) mk = 0;
        eps = fmaxf(BLUR2, e0 / (float)(1u << (2 * mk)));   // exact pow2 scale
    }
    const float ieps = 1.0f / eps;
    const float c    = 0.5f * ieps;
    const float cL   = c * L2E;

    // Stage column table: U_j = log2e * (h_j - c*col_j^2), h_j = b_log + g_j/eps
    const int t = threadIdx.x;
    for (int j = t; j < NP; j += 256) {
        float cj = colc[j];
        float hj = (round == 0) ? HLOG : fmaf(hsrc[j], ieps, HLOG);
        float U  = L2E * hj - cL * cj * cj;
        cu[j] = make_float2(cj, U);
    }
    __syncthreads();

    const int lc = t & 3;        // lane within row group
    const int lr = t >> 2;       // row within block, 0..63
    const int i  = rowblk * 64 + lr;
    const float xi = rowc[i];
    const float S  = 2.0f * cL * xi;       // exponent = U_j + S*col_j + Kc
    const float Kc = -cL * xi * xi;

    const float4* p = (const float4*)cu;   // NP/2 = 768 entries, 2 cols each

    // pass 1: max
    float m0 = -INFINITY, m1 = -INFINITY;
    #pragma unroll 4
    for (int q = lc; q < NP / 2; q += 4) {
        float4 a = p[q];
        m0 = fmaxf(m0, fmaf(S, a.x, a.y));
        m1 = fmaxf(m1, fmaf(S, a.z, a.w));
    }
    float m = fmaxf(m0, m1);
    m = fmaxf(m, __shfl_xor(m, 1));
    m = fmaxf(m, __shfl_xor(m, 2));

    // pass 2: sum of 2^(v-m)
    float s0 = 0.0f, s1 = 0.0f;
    #pragma unroll 4
    for (int q = lc; q < NP / 2; q += 4) {
        float4 a = p[q];
        s0 += EXP2F(fmaf(S, a.x, a.y) - m);
        s1 += EXP2F(fmaf(S, a.z, a.w) - m);
    }
    float s = s0 + s1;
    s += __shfl_xor(s, 1);
    s += __shfl_xor(s, 2);

    const float ft = -eps * LN2 * (m + __log2f(s) + Kc);

    if (round < 17) {
        if (lc == 0) {
            float v = (round == 0) ? ft : 0.5f * (oldb[i] + ft);
            obuf[i] = v;
        }
    } else {
        // fused reduction: sum of all f_fin and g_fin entries, scaled by 1/N
        float v = (lc == 0) ? ft : 0.0f;
        for (int o = 1; o < 64; o <<= 1) v += __shfl_xor(v, o);
        const int w = t >> 6;
        if ((t & 63) == 0) wsum[w] = v;
        __syncthreads();
        if (t == 0) {
            float tot = (wsum[0] + wsum[1]) + (wsum[2] + wsum[3]);
            atomicAdd(out, tot * (1.0f / NP));
        }
    }
}

extern "C" void kernel_launch(void* const* d_in, const int* in_sizes, int n_in,
                              void* d_out, int out_size, void* d_ws, size_t ws_size,
                              hipStream_t stream) {
    const float* x = (const float*)d_in[0];
    const float* y = (const float*)d_in[1];
    float* out = (float*)d_out;
    float* ws  = (float*)d_ws;

    hipMemsetAsync(out, 0, sizeof(float), stream);
    hipLaunchKernelGGL(sk_setup, dim3(BN), dim3(256), 0, stream, x, y, ws);
    for (int r = 0; r < 18; ++r) {
        hipLaunchKernelGGL(sk_round, dim3(768), dim3(256), 0, stream,
                           x, y, ws, out, r);
    }
}

// Round 2
// 370.268 us; speedup vs baseline: 1.0826x; 1.0826x over previous
//
#include <hip/hip_runtime.h>
#include <math.h>

// Sinkhorn loss, B=16 batches of N=1536 1D points, fp32.
// 18 softmin rounds: round 0 = init (h = b_log), rounds 1..16 = scan steps
// (Jacobi update, f_new = 0.5*(f_old + ft)), round 17 = final extrapolation
// at eps = blur^2 fused with the mean/sum reduction into d_out[0].
//
// R1: register-tile 8 rows/thread so each LDS column read (float4 = 2 cols)
// feeds 8 rows -> LDS traffic /8 (R0 was LDS-delivery-bound at ~22us/round).
//
// ws layout (floats): eps0[16] | F0[B*N] | F1[B*N] | G0[B*N] | G1[B*N]

static constexpr int   BN    = 16;
static constexpr int   NP    = 1536;
static constexpr float BLUR2 = 0.0025f;                 // blur^2
static constexpr float L2E   = 1.4426950408889634f;     // log2(e)
static constexpr float LN2   = 0.6931471805599453f;     // ln(2)
static constexpr float HLOG  = -7.33693691f;            // -log(1536)

#if defined(__has_builtin)
#if __has_builtin(__builtin_amdgcn_exp2f)
#define EXP2F(x) __builtin_amdgcn_exp2f(x)
#else
#define EXP2F(x) exp2f(x)
#endif
#else
#define EXP2F(x) exp2f(x)
#endif

__global__ __launch_bounds__(256) void sk_setup(const float* __restrict__ x,
                                                const float* __restrict__ y,
                                                float* __restrict__ eps0) {
    const int b = blockIdx.x;
    const int t = threadIdx.x;
    float mn = INFINITY, mx = -INFINITY;
    for (int j = t; j < NP; j += 256) {
        float xv = x[b * NP + j], yv = y[b * NP + j];
        mn = fminf(mn, fminf(xv, yv));
        mx = fmaxf(mx, fmaxf(xv, yv));
    }
    for (int o = 1; o < 64; o <<= 1) {
        mn = fminf(mn, __shfl_xor(mn, o));
        mx = fmaxf(mx, __shfl_xor(mx, o));
    }
    __shared__ float smn[4], smx[4];
    const int w = t >> 6;
    if ((t & 63) == 0) { smn[w] = mn; smx[w] = mx; }
    __syncthreads();
    if (t == 0) {
        mn = fminf(fminf(smn[0], smn[1]), fminf(smn[2], smn[3]));
        mx = fmaxf(fmaxf(smx[0], smx[1]), fmaxf(smx[2], smx[3]));
        float d = mx - mn;
        eps0[b] = d * d;
    }
}

// grid = 768 blocks: batch (16) x {dir f: 24, dir g: 24} row-blocks of 64 rows.
// Block = 8 groups x 32 lanes; group g owns 8 rows, lanes split the columns.
__global__ __launch_bounds__(256) void sk_round(const float* __restrict__ x,
                                                const float* __restrict__ y,
                                                float* __restrict__ ws,
                                                float* __restrict__ out,
                                                int round) {
    __shared__ __align__(16) float2 cu[NP];   // (col_coord_j, U_j) ; 12 KB
    __shared__ float wsum[4];

    const int blk    = blockIdx.x;       // 0..767
    const int batch  = blk / 48;
    const int rb     = blk % 48;
    const int dir    = (rb < 24) ? 0 : 1;
    const int rowblk = rb - dir * 24;    // 0..23

    float* F0 = ws + 16;
    float* F1 = F0 + BN * NP;
    float* G0 = F1 + BN * NP;
    float* G1 = G0 + BN * NP;
    const int ri = (round + 1) & 1;      // read parity
    const int wi = round & 1;            // write parity
    float* Fr = ri ? F1 : F0;  float* Fw = wi ? F1 : F0;
    float* Gr = ri ? G1 : G0;  float* Gw = wi ? G1 : G0;

    const float* colc; const float* rowc; const float* hsrc;
    float* obuf; const float* oldb;
    if (dir == 0) { // ft rows: rows over x_i, cols over y_j, h from g
        colc = y + batch * NP; rowc = x + batch * NP;
        hsrc = Gr + batch * NP; obuf = Fw + batch * NP; oldb = Fr + batch * NP;
    } else {        // gt rows: rows over y_i, cols over x_j, h from f
        colc = x + batch * NP; rowc = y + batch * NP;
        hsrc = Fr + batch * NP; obuf = Gw + batch * NP; oldb = Gr + batch * NP;
    }

    // eps schedule: eps_k = max(blur^2, eps0 * 0.25^max(k-1,0)); round r in
    // [1,16] is scan step k=r-1; round 0 uses eps_arr[0]; round 17 uses blur^2.
    const float e0 = ws[batch];
    float eps;
    if (round == 0)       eps = fmaxf(BLUR2, e0);
    else if (round >= 17) eps = BLUR2;
    else {
        int mk = round - 2; if (mk < 0) mk = 0;
        eps = fmaxf(BLUR2, e0 / (float)(1u << (2 * mk)));   // exact pow2 scale
    }
    const float ieps = 1.0f / eps;
    const float c    = 0.5f * ieps;
    const float cL   = c * L2E;

    // Stage column table: U_j = log2e * (h_j - c*col_j^2), h_j = b_log + g_j/eps
    const int t = threadIdx.x;
    for (int j = t; j < NP; j += 256) {
        float cj = colc[j];
        float hj = (round == 0) ? HLOG : fmaf(hsrc[j], ieps, HLOG);
        float U  = fmaf(L2E, hj, -cL * cj * cj);
        cu[j] = make_float2(cj, U);
    }
    __syncthreads();

    const int l  = t & 31;       // lane within group: splits columns
    const int g  = t >> 5;       // group 0..7: owns 8 rows
    const int i0 = rowblk * 64 + g * 8;

    float S[8], Kc[8];
    #pragma unroll
    for (int r = 0; r < 8; ++r) {
        float xi = rowc[i0 + r];
        S[r]  = 2.0f * cL * xi;          // exponent = U_j + S*col_j + Kc
        Kc[r] = -cL * xi * xi;
    }

    const float4* p = (const float4*)cu;   // NP/2 = 768 entries, 2 cols each

    // pass 1: max (each 16B LDS read feeds 8 rows x 2 cols)
    float m[8];
    #pragma unroll
    for (int r = 0; r < 8; ++r) m[r] = -INFINITY;
    #pragma unroll 2
    for (int q = l; q < NP / 2; q += 32) {
        float4 a = p[q];
        #pragma unroll
        for (int r = 0; r < 8; ++r) {
            m[r] = fmaxf(m[r], fmaf(S[r], a.x, a.y));
            m[r] = fmaxf(m[r], fmaf(S[r], a.z, a.w));
        }
    }
    #pragma unroll
    for (int r = 0; r < 8; ++r) {
        m[r] = fmaxf(m[r], __shfl_xor(m[r], 1));
        m[r] = fmaxf(m[r], __shfl_xor(m[r], 2));
        m[r] = fmaxf(m[r], __shfl_xor(m[r], 4));
        m[r] = fmaxf(m[r], __shfl_xor(m[r], 8));
        m[r] = fmaxf(m[r], __shfl_xor(m[r], 16));
    }

    // pass 2: sum of 2^(v-m)
    float s[8];
    #pragma unroll
    for (int r = 0; r < 8; ++r) s[r] = 0.0f;
    #pragma unroll 2
    for (int q = l; q < NP / 2; q += 32) {
        float4 a = p[q];
        #pragma unroll
        for (int r = 0; r < 8; ++r) {
            s[r] += EXP2F(fmaf(S[r], a.x, a.y) - m[r]);
            s[r] += EXP2F(fmaf(S[r], a.z, a.w) - m[r]);
        }
    }
    #pragma unroll
    for (int r = 0; r < 8; ++r) {
        s[r] += __shfl_xor(s[r], 1);
        s[r] += __shfl_xor(s[r], 2);
        s[r] += __shfl_xor(s[r], 4);
        s[r] += __shfl_xor(s[r], 8);
        s[r] += __shfl_xor(s[r], 16);
    }

    // lane l (<8) finalizes row r = l of its group (log2 work split over lanes)
    float ftv = 0.0f;
    if (l < 8) {
        const int r = l;
        ftv = -eps * LN2 * (m[r] + __log2f(s[r]) + Kc[r]);
    }

    if (round < 17) {
        if (l < 8) {
            const int i = i0 + l;
            obuf[i] = (round == 0) ? ftv : 0.5f * (oldb[i] + ftv);
        }
    } else {
        // fused reduction: sum of all f_fin and g_fin entries, scaled by 1/N
        float v = ftv;
        for (int o = 1; o < 64; o <<= 1) v += __shfl_xor(v, o);
        const int w = t >> 6;
        if ((t & 63) == 0) wsum[w] = v;
        __syncthreads();
        if (t == 0) {
            float tot = (wsum[0] + wsum[1]) + (wsum[2] + wsum[3]);
            atomicAdd(out, tot * (1.0f / NP));
        }
    }
}

extern "C" void kernel_launch(void* const* d_in, const int* in_sizes, int n_in,
                              void* d_out, int out_size, void* d_ws, size_t ws_size,
                              hipStream_t stream) {
    const float* x = (const float*)d_in[0];
    const float* y = (const float*)d_in[1];
    float* out = (float*)d_out;
    float* ws  = (float*)d_ws;

    hipMemsetAsync(out, 0, sizeof(float), stream);
    hipLaunchKernelGGL(sk_setup, dim3(BN), dim3(256), 0, stream, x, y, ws);
    for (int r = 0; r < 18; ++r) {
        hipLaunchKernelGGL(sk_round, dim3(768), dim3(256), 0, stream,
                           x, y, ws, out, r);
    }
}